// Round 5
// baseline (443.806 us; speedup 1.0000x reference)
//
#include <hip/hip_runtime.h>
#include <stdint.h>

typedef unsigned int u32;
typedef unsigned short u16;

#define C_   256
#define C8_  32
#define H_   128
#define W_   128
#define HW_  (H_*W_)

typedef __bf16 bf16x8_t __attribute__((ext_vector_type(8)));
typedef float  f32x4_t  __attribute__((ext_vector_type(4)));

__device__ __forceinline__ float bf2f(u32 u) {
    union { u32 i; float f; } v; v.i = u << 16; return v.f;
}
__device__ __forceinline__ u16 f2bf(float f) {
    union { float f; u32 i; } v; v.f = f;
    u32 r = v.i + 0x7fffu + ((v.i >> 16) & 1u);
    return (u16)(r >> 16);
}
__device__ __forceinline__ bf16x8_t ld_frag(const u16* p) {
    union { uint4 u; bf16x8_t b; } x; x.u = *(const uint4*)p; return x.b;
}

// ws layout (bytes)
#define WS_XF1   0                  // (unused now; kept for layout stability)
#define WS_XF2   67108864           // bf16 [2048][64][256]  = 67108864
#define WS_WBC2  134217728          // bf16 [64][256]        = 32768
#define WS_WD2   (134217728+32768)  // bf16 [256][256]       = 131072
#define WS_GEN   134479872          // general path scratch (only touched if alpha1 != 0)
#define WS_FB1   WS_GEN                       // fp32 [512][32][256] = 16777216
#define WS_FC1   (WS_GEN + 16777216)          // fp32 [512][32][256] = 16777216
#define WS_FD1   (WS_GEN + 33554432)          // bf16 [512][256][256] = 67108864

// ---------------------------------------------------------------------------
// Kw: pack PAM2 weights to bf16. Wbc2 rows 0..31 = Wb2, 32..63 = Wc2.
// ---------------------------------------------------------------------------
__global__ __launch_bounds__(256) void k_wpack(
    const float* __restrict__ Wb2, const float* __restrict__ Wc2,
    const float* __restrict__ Wd2, u16* __restrict__ Wbc2, u16* __restrict__ Wd2b)
{
    int gid = blockIdx.x * 256 + threadIdx.x;
    if (gid < 16384) {
        int o = gid >> 8, c = gid & 255;
        float v = (o < 32) ? Wb2[o*256 + c] : Wc2[(o-32)*256 + c];
        Wbc2[gid] = f2bf(v);
    } else if (gid < 81920) {
        Wd2b[gid - 16384] = f2bf(Wd2[gid - 16384]);
    }
}

// ---------------------------------------------------------------------------
// K0: gather/transpose x (fp32 NCHW) -> xf2 bf16 [b2=(n,qh,qw)][l2=(ph,pw)][c]
// xf1 removed (dead); halves store traffic (R2/R4: pam2 FETCH 67->56 MB).
// ---------------------------------------------------------------------------
__global__ __launch_bounds__(256) void k_gather(
    const float* __restrict__ x, const float* __restrict__ alpha1,
    u16* __restrict__ xf2)
{
    if (alpha1[0] != 0.f) return;   // general path: k_attn_fe1 writes xf2
    __shared__ __align__(16) u16 xt[128 * 130];
    int id = blockIdx.x;
    int n = id >> 8, h = (id >> 1) & 127, ch = id & 1;
    int qh = h >> 3, ph = h & 7;
    const float* xb = x + (((size_t)(n*256 + ch*128)) * 128 + h) * 128;
    #pragma unroll
    for (int s = 0; s < 16; ++s) {
        int idx = threadIdx.x + 256 * s;     // 0..4095
        int cc = idx >> 5, w4 = idx & 31;
        float4 v = *(const float4*)(xb + (size_t)cc * HW_ + w4 * 4);
        u32 p0 = (u32)f2bf(v.x) | ((u32)f2bf(v.y) << 16);
        u32 p1 = (u32)f2bf(v.z) | ((u32)f2bf(v.w) << 16);
        ((u32*)xt)[cc * 65 + w4 * 2]     = p0;
        ((u32*)xt)[cc * 65 + w4 * 2 + 1] = p1;
    }
    __syncthreads();
    int t = threadIdx.x;
    int r = t & 127, seg = t >> 7;         // r -> (qw,pw); seg -> c-half of half
    int qw = r >> 3, pw = r & 7;
    int wcol = qw * 8 + pw;
    u32 buf[32];
    #pragma unroll
    for (int k = 0; k < 32; ++k) {
        u16 a = xt[(seg * 64 + 2 * k)     * 130 + wcol];
        u16 b = xt[(seg * 64 + 2 * k + 1) * 130 + wcol];
        buf[k] = (u32)a | ((u32)b << 16);
    }
    size_t b2 = (size_t)n * 256 + qh * 16 + qw;
    size_t l2 = ph * 8 + pw;
    u32* d2 = (u32*)(xf2 + (b2 * 64 + l2) * 256 + ch * 128 + seg * 64);
    #pragma unroll
    for (int k = 0; k < 32; ++k) d2[k] = buf[k];
}

// ---------------------------------------------------------------------------
// General-path PAM1 kernels — grid-strided so the alpha1==0 early-exit costs
// only gridDim blocks (512) instead of 4096/8192 dispatched blocks.
// ---------------------------------------------------------------------------
__global__ __launch_bounds__(256) void k_fbfc1(
    const float* __restrict__ x, const float* __restrict__ Wb,
    const float* __restrict__ bb, const float* __restrict__ Wc,
    const float* __restrict__ bc, float* __restrict__ fb, float* __restrict__ fc,
    const float* __restrict__ alpha)
{
    if (alpha[0] == 0.f) return;
    __shared__ __align__(16) float xt[C_ * 32];
    const int t = threadIdx.x;
    for (int id = blockIdx.x; id < 8 * 512; id += gridDim.x) {
        const int tile = id & 7;
        const int b = id >> 3;
        const int n = b >> 6, ph = (b >> 3) & 7, pw = b & 7;
        const float* xb = x + (size_t)n * C_ * HW_;
        #pragma unroll
        for (int s = 0; s < 32; ++s) {
            int i = t + 256 * s;
            int c = i >> 5, l = i & 31;
            int l1 = tile * 32 + l;
            int qh = l1 >> 4, qw = l1 & 15;
            xt[c * 32 + l] = xb[(size_t)c * HW_ + (qh * 8 + ph) * W_ + (qw * 8 + pw)];
        }
        __syncthreads();
        const int l = t & 31;
        const int og = t >> 5;
        const float* Wp = (og < 4) ? Wb : Wc;
        const float* bp = (og < 4) ? bb : bc;
        float* op = (og < 4) ? fb : fc;
        const int ob = (og & 3) * 8;
        float acc[8];
        #pragma unroll
        for (int j = 0; j < 8; ++j) acc[j] = bp[ob + j];
        for (int c = 0; c < C_; ++c) {
            float xv = xt[c * 32 + l];
            #pragma unroll
            for (int j = 0; j < 8; ++j)
                acc[j] += Wp[(ob + j) * C_ + c] * xv;
        }
        #pragma unroll
        for (int j = 0; j < 8; ++j)
            op[((size_t)b * C8_ + ob + j) * 256 + tile * 32 + l] = acc[j];
        __syncthreads();   // xt reused next iteration
    }
}

__global__ __launch_bounds__(256) void k_fd1(
    const float* __restrict__ x, const float* __restrict__ Wd,
    const float* __restrict__ bd, u16* __restrict__ fd,
    const float* __restrict__ alpha)
{
    if (alpha[0] == 0.f) return;
    __shared__ __align__(16) float xt[C_ * 32];
    const int t = threadIdx.x;
    for (int id = blockIdx.x; id < 8 * 512; id += gridDim.x) {
        const int tile = id & 7;
        const int b = id >> 3;
        const int n = b >> 6, ph = (b >> 3) & 7, pw = b & 7;
        const float* xb = x + (size_t)n * C_ * HW_;
        #pragma unroll
        for (int s = 0; s < 32; ++s) {
            int i = t + 256 * s;
            int k = i >> 5, m = i & 31;
            int l1 = tile * 32 + m;
            int qh = l1 >> 4, qw = l1 & 15;
            xt[k * 32 + m] = xb[(size_t)k * HW_ + (qh * 8 + ph) * W_ + (qw * 8 + pw)];
        }
        __syncthreads();
        const int c = t;
        float acc[32];
        #pragma unroll
        for (int m = 0; m < 32; ++m) acc[m] = 0.f;
        const float* wrow = Wd + c * C_;
        for (int k = 0; k < C_; k += 4) {
            float4 w = *(const float4*)(wrow + k);
            float wk[4] = {w.x, w.y, w.z, w.w};
            #pragma unroll
            for (int kk = 0; kk < 4; ++kk) {
                const float4* xr = (const float4*)(xt + (k + kk) * 32);
                float wv = wk[kk];
                #pragma unroll
                for (int qq = 0; qq < 8; ++qq) {
                    float4 xv = xr[qq];
                    acc[qq*4+0] += wv * xv.x;
                    acc[qq*4+1] += wv * xv.y;
                    acc[qq*4+2] += wv * xv.z;
                    acc[qq*4+3] += wv * xv.w;
                }
            }
        }
        const float bdv = bd[c];
        u32* dst = (u32*)(fd + ((size_t)b * C_ + c) * 256 + tile * 32);
        #pragma unroll
        for (int m = 0; m < 16; ++m) {
            u32 lo = f2bf(acc[2*m] + bdv);
            u32 hi = f2bf(acc[2*m+1] + bdv);
            dst[m] = lo | (hi << 16);
        }
        __syncthreads();   // xt reused next iteration
    }
}

__global__ __launch_bounds__(256) void k_attn_fe1(
    const float* __restrict__ x, const float* __restrict__ fb,
    const float* __restrict__ fc, const u16* __restrict__ fd,
    const float* __restrict__ alpha, u16* __restrict__ xf2)
{
    if (alpha[0] == 0.f) return;
    __shared__ __align__(16) float smem[12800];
    float* fbt = smem;
    float* fct = smem + 512;
    float* S   = smem + 8704;
    float* attnT = smem + 512;
    const int t = threadIdx.x;
    for (int id = blockIdx.x; id < 16 * 512; id += gridDim.x) {
        const int tile = id & 15;
        const int b = id >> 4;
        #pragma unroll
        for (int s = 0; s < 2; ++s) {
            int j = t + 256 * s;
            int o = j >> 4, l = j & 15;
            fbt[o * 16 + l] = fb[((size_t)b * C8_ + o) * 256 + tile * 16 + l];
        }
        #pragma unroll
        for (int s = 0; s < 32; ++s) {
            int j = t + 256 * s;
            int o = j >> 8, m = j & 255;
            fct[o * 256 + m] = fc[((size_t)b * C8_ + o) * 256 + m];
        }
        __syncthreads();
        {
            const int lane = t & 63, wv = t >> 6;
            float acc[4][4];
            #pragma unroll
            for (int i = 0; i < 4; ++i)
                #pragma unroll
                for (int j = 0; j < 4; ++j) acc[i][j] = 0.f;
            for (int o = 0; o < 32; ++o) {
                float cv[4];
                #pragma unroll
                for (int j = 0; j < 4; ++j) cv[j] = fct[o * 256 + lane + 64 * j];
                #pragma unroll
                for (int i = 0; i < 4; ++i) {
                    float a = fbt[o * 16 + wv * 4 + i];
                    #pragma unroll
                    for (int j = 0; j < 4; ++j) acc[i][j] += a * cv[j];
                }
            }
            #pragma unroll
            for (int i = 0; i < 4; ++i)
                #pragma unroll
                for (int j = 0; j < 4; ++j)
                    S[(wv * 4 + i) * 256 + lane + 64 * j] = acc[i][j];
        }
        __syncthreads();
        {
            const int r = t >> 4, k = t & 15;
            float vals[16];
            float mx = -1e30f;
            #pragma unroll
            for (int j = 0; j < 16; ++j) {
                vals[j] = S[r * 256 + k + 16 * j];
                mx = fmaxf(mx, vals[j]);
            }
            mx = fmaxf(mx, __shfl_xor(mx, 1, 16));
            mx = fmaxf(mx, __shfl_xor(mx, 2, 16));
            mx = fmaxf(mx, __shfl_xor(mx, 4, 16));
            mx = fmaxf(mx, __shfl_xor(mx, 8, 16));
            float sum = 0.f;
            #pragma unroll
            for (int j = 0; j < 16; ++j) { vals[j] = __expf(vals[j] - mx); sum += vals[j]; }
            sum += __shfl_xor(sum, 1, 16);
            sum += __shfl_xor(sum, 2, 16);
            sum += __shfl_xor(sum, 4, 16);
            sum += __shfl_xor(sum, 8, 16);
            const float inv = 1.0f / sum;
            #pragma unroll
            for (int j = 0; j < 16; ++j)
                attnT[(k + 16 * j) * 16 + r] = vals[j] * inv;
        }
        __syncthreads();
        const int c = t;
        float acc[16];
        #pragma unroll
        for (int i = 0; i < 16; ++i) acc[i] = 0.f;
        const u16* fdrow = fd + ((size_t)b * C_ + c) * 256;
        for (int m = 0; m < 256; m += 4) {
            uint2 p = *(const uint2*)(fdrow + m);
            float wm[4] = { bf2f(p.x & 0xffffu), bf2f(p.x >> 16),
                            bf2f(p.y & 0xffffu), bf2f(p.y >> 16) };
            #pragma unroll
            for (int mm = 0; mm < 4; ++mm) {
                const float4* ar = (const float4*)(attnT + (m + mm) * 16);
                float wv = wm[mm];
                #pragma unroll
                for (int qq = 0; qq < 4; ++qq) {
                    float4 av = ar[qq];
                    acc[qq*4+0] += wv * av.x;
                    acc[qq*4+1] += wv * av.y;
                    acc[qq*4+2] += wv * av.z;
                    acc[qq*4+3] += wv * av.w;
                }
            }
        }
        const float al = alpha[0];
        const int n = b >> 6, ph = (b >> 3) & 7, pw = b & 7;
        const int l2 = ph * 8 + pw;
        const float* xb = x + (size_t)n * C_ * HW_ + (size_t)c * HW_;
        #pragma unroll
        for (int i = 0; i < 16; ++i) {
            int l1 = tile * 16 + i;
            int qh = l1 >> 4, qw = l1 & 15;
            float xv = xb[(qh * 8 + ph) * W_ + (qw * 8 + pw)];
            size_t b2 = (size_t)n * 256 + qh * 16 + qw;
            xf2[(b2 * 64 + l2) * 256 + c] = f2bf(al * acc[i] + xv);
        }
        __syncthreads();   // smem reused next iteration
    }
}

// ---------------------------------------------------------------------------
// K6: fully-fused PAM2 per b2.
// R5: phases 1 and 5 MERGED into one K-loop (phase 5 depends only on
// xf2/Wd2): 20 MFMA per 13 16B-loads, 80 accumulators of ILP, one pass over
// xf2, and ONE full barrier instead of two (fbcT+fd2 both stored before it;
// phase 6's attn reads are wave-local). No setprio (R4: it blocked load
// hoisting, VGPR 108->96, pam2 139->160 us). LDS layout = R0 (55296 B,
// 2 blocks/CU — LDS-bound, so extra VGPRs are free).
// ---------------------------------------------------------------------------
#define FDSLAB 0
#define FBCT   18432
#define ATTN   23040

__global__ __launch_bounds__(256) void k_pam2_fused(
    const u16* __restrict__ xf2, const u16* __restrict__ Wbc2,
    const u16* __restrict__ Wd2, const float* __restrict__ bb2,
    const float* __restrict__ bc2, const float* __restrict__ bd2,
    const float* __restrict__ alpha2, float* __restrict__ out)
{
    __shared__ __align__(16) u16 lds[27648];
    const int b2 = blockIdx.x;
    const int n = b2 >> 8, qh = (b2 >> 4) & 15, qw = b2 & 15;
    const int t = threadIdx.x;
    const int w = t >> 6, lane = t & 63;
    const int q = lane >> 4, i = lane & 15;
    const int ls = w * 16;   // wave's l-strip (fbc2 / S / fe rows)
    const int cs = w * 64;   // wave's c-strip (fd2 rows)
    const u16* xrow0 = xf2 + (size_t)b2 * 64 * 256;

    // ---- merged phase 1+5:
    //   acc1[mt]      : fbc2[o=mt*16..][l-strip]   (M=64 o, N=16 l, K=256)
    //   acc2[mt][nt]  : fd2[c=cs+mt*16..][m=nt*16..] (M=64 c, N=64 m, K=256)
    f32x4_t acc1[4];
    f32x4_t acc2[4][4];
    #pragma unroll
    for (int mt = 0; mt < 4; ++mt) {
        acc1[mt] = (f32x4_t){0.f,0.f,0.f,0.f};
        #pragma unroll
        for (int nt = 0; nt < 4; ++nt) acc2[mt][nt] = (f32x4_t){0.f,0.f,0.f,0.f};
    }
    for (int ks = 0; ks < 8; ++ks) {
        int kb = ks * 32 + q * 8;
        bf16x8_t bfr[4];
        #pragma unroll
        for (int nt = 0; nt < 4; ++nt)
            bfr[nt] = ld_frag(xrow0 + (size_t)(nt * 16 + i) * 256 + kb);
        // explicit reload of this wave's l-strip row (avoids runtime bfr[w])
        bf16x8_t b1 = ld_frag(xrow0 + (size_t)(ls + i) * 256 + kb);
        #pragma unroll
        for (int mt = 0; mt < 4; ++mt) {
            bf16x8_t afrd = ld_frag(Wd2 + (size_t)(cs + mt * 16 + i) * 256 + kb);
            #pragma unroll
            for (int nt = 0; nt < 4; ++nt)
                acc2[mt][nt] = __builtin_amdgcn_mfma_f32_16x16x32_bf16(afrd, bfr[nt], acc2[mt][nt], 0, 0, 0);
            bf16x8_t afrb = ld_frag(Wbc2 + (mt * 16 + i) * 256 + kb);
            acc1[mt] = __builtin_amdgcn_mfma_f32_16x16x32_bf16(afrb, b1, acc1[mt], 0, 0, 0);
        }
    }
    // bias + transpose-store fbcT[l][o]
    #pragma unroll
    for (int mt = 0; mt < 4; ++mt) {
        #pragma unroll
        for (int r = 0; r < 4; ++r) {
            int o = mt * 16 + q * 4 + r;
            float bv = (o < 32) ? bb2[o] : bc2[o - 32];
            lds[FBCT + (ls + i) * 72 + o] = f2bf(acc1[mt][r] + bv);
        }
    }
    // bias + store fd2 slab [c][m]
    #pragma unroll
    for (int mt = 0; mt < 4; ++mt) {
        #pragma unroll
        for (int r = 0; r < 4; ++r) {
            int c = cs + mt * 16 + q * 4 + r;
            float bv = bd2[c];
            #pragma unroll
            for (int nt = 0; nt < 4; ++nt)
                lds[FDSLAB + c * 72 + nt * 16 + i] = f2bf(acc2[mt][nt][r] + bv);
        }
    }
    __syncthreads();   // the ONLY full barrier before the epilogue

    // ---- phase 3: S[l][m] = fbT @ fcT^T (M=16 l, N=64 m, K=32 o)
    f32x4_t accS[4];
    #pragma unroll
    for (int nt = 0; nt < 4; ++nt) accS[nt] = (f32x4_t){0.f,0.f,0.f,0.f};
    {
        bf16x8_t afr = ld_frag(&lds[FBCT + (ls + i) * 72 + q * 8]);
        #pragma unroll
        for (int nt = 0; nt < 4; ++nt) {
            bf16x8_t bfr = ld_frag(&lds[FBCT + (nt * 16 + i) * 72 + 32 + q * 8]);
            accS[nt] = __builtin_amdgcn_mfma_f32_16x16x32_bf16(afr, bfr, accS[nt], 0, 0, 0);
        }
    }
    // ---- phase 4: softmax rows -> attn bf16 [l][m] (wave-local rows)
    #pragma unroll
    for (int r = 0; r < 4; ++r) {
        int l = ls + q * 4 + r;
        float mx = accS[0][r];
        #pragma unroll
        for (int nt = 1; nt < 4; ++nt) mx = fmaxf(mx, accS[nt][r]);
        mx = fmaxf(mx, __shfl_xor(mx, 1));
        mx = fmaxf(mx, __shfl_xor(mx, 2));
        mx = fmaxf(mx, __shfl_xor(mx, 4));
        mx = fmaxf(mx, __shfl_xor(mx, 8));
        float e[4], sum = 0.f;
        #pragma unroll
        for (int nt = 0; nt < 4; ++nt) { e[nt] = __expf(accS[nt][r] - mx); sum += e[nt]; }
        sum += __shfl_xor(sum, 1);
        sum += __shfl_xor(sum, 2);
        sum += __shfl_xor(sum, 4);
        sum += __shfl_xor(sum, 8);
        float inv = 1.0f / sum;
        #pragma unroll
        for (int nt = 0; nt < 4; ++nt)
            lds[ATTN + l * 72 + nt * 16 + i] = f2bf(e[nt] * inv);
    }

    // ---- phase 6: fe[l][c] = attn @ fd^T (M=16 l, N=256 c, K=64 m)
    // attn rows (ls+i) are wave-local (written in phase 4 by this wave);
    // FDSLAB cross-wave reads covered by the barrier above.
    f32x4_t accE[16];
    #pragma unroll
    for (int nt = 0; nt < 16; ++nt) accE[nt] = (f32x4_t){0.f,0.f,0.f,0.f};
    #pragma unroll
    for (int ks = 0; ks < 2; ++ks) {
        int kb = ks * 32 + q * 8;
        bf16x8_t afr = ld_frag(&lds[ATTN + (ls + i) * 72 + kb]);
        #pragma unroll
        for (int nt = 0; nt < 16; ++nt) {
            bf16x8_t bfr = ld_frag(&lds[FDSLAB + (nt * 16 + i) * 72 + kb]);
            accE[nt] = __builtin_amdgcn_mfma_f32_16x16x32_bf16(afr, bfr, accE[nt], 0, 0, 0);
        }
    }

    // ---- phase 7: residual + write out (fp32 NCHW) via LDS staging
    const float al = alpha2[0];
    float vals[64];
    #pragma unroll
    for (int nt = 0; nt < 16; ++nt) {
        #pragma unroll
        for (int r = 0; r < 4; ++r) {
            int l = ls + q * 4 + r;
            int c = nt * 16 + i;
            float xv = bf2f(xrow0[(size_t)l * 256 + c]);
            vals[nt * 4 + r] = al * accE[nt][r] + xv;
        }
    }
    float* stg = (float*)lds;   // overlays fdslab region: [64][133] floats
    for (int h = 0; h < 2; ++h) {
        __syncthreads();
        #pragma unroll
        for (int nt = h * 8; nt < h * 8 + 8; ++nt) {
            #pragma unroll
            for (int r = 0; r < 4; ++r) {
                int l = ls + q * 4 + r;
                int cc = nt * 16 + i - h * 128;
                stg[l * 133 + cc] = vals[nt * 4 + r];
            }
        }
        __syncthreads();
        int ph = lane >> 3, pw = lane & 7;
        for (int j = 0; j < 32; ++j) {
            int c = h * 128 + w * 32 + j;
            float v = stg[lane * 133 + (c - h * 128)];
            out[(((size_t)n * 256 + c) * 128 + qh * 8 + ph) * 128 + qw * 8 + pw] = v;
        }
    }
}

extern "C" void kernel_launch(void* const* d_in, const int* in_sizes, int n_in,
                              void* d_out, int out_size, void* d_ws, size_t ws_size,
                              hipStream_t stream)
{
    const float* x   = (const float*)d_in[0];
    const float* Wb1 = (const float*)d_in[1];
    const float* bb1 = (const float*)d_in[2];
    const float* Wc1 = (const float*)d_in[3];
    const float* bc1 = (const float*)d_in[4];
    const float* Wd1 = (const float*)d_in[5];
    const float* bd1 = (const float*)d_in[6];
    const float* a1  = (const float*)d_in[7];
    const float* Wb2 = (const float*)d_in[8];
    const float* bb2 = (const float*)d_in[9];
    const float* Wc2 = (const float*)d_in[10];
    const float* bc2 = (const float*)d_in[11];
    const float* Wd2 = (const float*)d_in[12];
    const float* bd2 = (const float*)d_in[13];
    const float* a2  = (const float*)d_in[14];
    (void)in_sizes; (void)n_in; (void)out_size; (void)ws_size;

    char* ws = (char*)d_ws;
    u16*   xf2  = (u16*)(ws + WS_XF2);
    u16*   Wbc2 = (u16*)(ws + WS_WBC2);
    u16*   Wd2b = (u16*)(ws + WS_WD2);
    float* fb1  = (float*)(ws + WS_FB1);
    float* fc1  = (float*)(ws + WS_FC1);
    u16*   fd1  = (u16*)(ws + WS_FD1);
    float* out  = (float*)d_out;

    k_wpack<<<dim3(320), 256, 0, stream>>>(Wb2, Wc2, Wd2, Wbc2, Wd2b);
    k_gather<<<dim3(2048), 256, 0, stream>>>(x, a1, xf2);
    // PAM1 general path (grid-strided; early-exits when alpha1 == 0)
    k_fbfc1<<<dim3(512), 256, 0, stream>>>(x, Wb1, bb1, Wc1, bc1, fb1, fc1, a1);
    k_fd1<<<dim3(512), 256, 0, stream>>>(x, Wd1, bd1, fd1, a1);
    k_attn_fe1<<<dim3(512), 256, 0, stream>>>(x, fb1, fc1, fd1, a1, xf2);
    // PAM2 fused
    k_pam2_fused<<<dim3(2048), 256, 0, stream>>>(xf2, Wbc2, Wd2b, bb2, bc2, bd2, a2, out);
}

// Round 6
// 426.635 us; speedup vs baseline: 1.0402x; 1.0402x over previous
//
#include <hip/hip_runtime.h>
#include <stdint.h>

typedef unsigned int u32;
typedef unsigned short u16;

#define C_   256
#define C8_  32
#define H_   128
#define W_   128
#define HW_  (H_*W_)

typedef __bf16 bf16x8_t __attribute__((ext_vector_type(8)));
typedef float  f32x4_t  __attribute__((ext_vector_type(4)));

__device__ __forceinline__ float bf2f(u32 u) {
    union { u32 i; float f; } v; v.i = u << 16; return v.f;
}
__device__ __forceinline__ u16 f2bf(float f) {
    union { float f; u32 i; } v; v.f = f;
    u32 r = v.i + 0x7fffu + ((v.i >> 16) & 1u);
    return (u16)(r >> 16);
}
__device__ __forceinline__ bf16x8_t ld_frag(const u16* p) {
    union { uint4 u; bf16x8_t b; } x; x.u = *(const uint4*)p; return x.b;
}

// ws layout (bytes)
#define WS_XF1   0                  // (unused; layout stability)
#define WS_XF2   67108864           // bf16 [2048][64][256] — general path only now
#define WS_WBC2  134217728          // bf16 [64][256]        = 32768
#define WS_WD2   (134217728+32768)  // bf16 [256][256]       = 131072
#define WS_GEN   134479872          // general path scratch (only touched if alpha1 != 0)
#define WS_FB1   WS_GEN                       // fp32 [512][32][256] = 16777216
#define WS_FC1   (WS_GEN + 16777216)          // fp32 [512][32][256] = 16777216
#define WS_FD1   (WS_GEN + 33554432)          // bf16 [512][256][256] = 67108864

// ---------------------------------------------------------------------------
// Kw: pack PAM2 weights to bf16. Wbc2 rows 0..31 = Wb2, 32..63 = Wc2.
// ---------------------------------------------------------------------------
__global__ __launch_bounds__(256) void k_wpack(
    const float* __restrict__ Wb2, const float* __restrict__ Wc2,
    const float* __restrict__ Wd2, u16* __restrict__ Wbc2, u16* __restrict__ Wd2b)
{
    int gid = blockIdx.x * 256 + threadIdx.x;
    if (gid < 16384) {
        int o = gid >> 8, c = gid & 255;
        float v = (o < 32) ? Wb2[o*256 + c] : Wc2[(o-32)*256 + c];
        Wbc2[gid] = f2bf(v);
    } else if (gid < 81920) {
        Wd2b[gid - 16384] = f2bf(Wd2[gid - 16384]);
    }
}

// ---------------------------------------------------------------------------
// General-path PAM1 kernels — grid-strided; early-exit when alpha1 == 0.
// ---------------------------------------------------------------------------
__global__ __launch_bounds__(256) void k_fbfc1(
    const float* __restrict__ x, const float* __restrict__ Wb,
    const float* __restrict__ bb, const float* __restrict__ Wc,
    const float* __restrict__ bc, float* __restrict__ fb, float* __restrict__ fc,
    const float* __restrict__ alpha)
{
    if (alpha[0] == 0.f) return;
    __shared__ __align__(16) float xt[C_ * 32];
    const int t = threadIdx.x;
    for (int id = blockIdx.x; id < 8 * 512; id += gridDim.x) {
        const int tile = id & 7;
        const int b = id >> 3;
        const int n = b >> 6, ph = (b >> 3) & 7, pw = b & 7;
        const float* xb = x + (size_t)n * C_ * HW_;
        #pragma unroll
        for (int s = 0; s < 32; ++s) {
            int i = t + 256 * s;
            int c = i >> 5, l = i & 31;
            int l1 = tile * 32 + l;
            int qh = l1 >> 4, qw = l1 & 15;
            xt[c * 32 + l] = xb[(size_t)c * HW_ + (qh * 8 + ph) * W_ + (qw * 8 + pw)];
        }
        __syncthreads();
        const int l = t & 31;
        const int og = t >> 5;
        const float* Wp = (og < 4) ? Wb : Wc;
        const float* bp = (og < 4) ? bb : bc;
        float* op = (og < 4) ? fb : fc;
        const int ob = (og & 3) * 8;
        float acc[8];
        #pragma unroll
        for (int j = 0; j < 8; ++j) acc[j] = bp[ob + j];
        for (int c = 0; c < C_; ++c) {
            float xv = xt[c * 32 + l];
            #pragma unroll
            for (int j = 0; j < 8; ++j)
                acc[j] += Wp[(ob + j) * C_ + c] * xv;
        }
        #pragma unroll
        for (int j = 0; j < 8; ++j)
            op[((size_t)b * C8_ + ob + j) * 256 + tile * 32 + l] = acc[j];
        __syncthreads();
    }
}

__global__ __launch_bounds__(256) void k_fd1(
    const float* __restrict__ x, const float* __restrict__ Wd,
    const float* __restrict__ bd, u16* __restrict__ fd,
    const float* __restrict__ alpha)
{
    if (alpha[0] == 0.f) return;
    __shared__ __align__(16) float xt[C_ * 32];
    const int t = threadIdx.x;
    for (int id = blockIdx.x; id < 8 * 512; id += gridDim.x) {
        const int tile = id & 7;
        const int b = id >> 3;
        const int n = b >> 6, ph = (b >> 3) & 7, pw = b & 7;
        const float* xb = x + (size_t)n * C_ * HW_;
        #pragma unroll
        for (int s = 0; s < 32; ++s) {
            int i = t + 256 * s;
            int k = i >> 5, m = i & 31;
            int l1 = tile * 32 + m;
            int qh = l1 >> 4, qw = l1 & 15;
            xt[k * 32 + m] = xb[(size_t)k * HW_ + (qh * 8 + ph) * W_ + (qw * 8 + pw)];
        }
        __syncthreads();
        const int c = t;
        float acc[32];
        #pragma unroll
        for (int m = 0; m < 32; ++m) acc[m] = 0.f;
        const float* wrow = Wd + c * C_;
        for (int k = 0; k < C_; k += 4) {
            float4 w = *(const float4*)(wrow + k);
            float wk[4] = {w.x, w.y, w.z, w.w};
            #pragma unroll
            for (int kk = 0; kk < 4; ++kk) {
                const float4* xr = (const float4*)(xt + (k + kk) * 32);
                float wv = wk[kk];
                #pragma unroll
                for (int qq = 0; qq < 8; ++qq) {
                    float4 xv = xr[qq];
                    acc[qq*4+0] += wv * xv.x;
                    acc[qq*4+1] += wv * xv.y;
                    acc[qq*4+2] += wv * xv.z;
                    acc[qq*4+3] += wv * xv.w;
                }
            }
        }
        const float bdv = bd[c];
        u32* dst = (u32*)(fd + ((size_t)b * C_ + c) * 256 + tile * 32);
        #pragma unroll
        for (int m = 0; m < 16; ++m) {
            u32 lo = f2bf(acc[2*m] + bdv);
            u32 hi = f2bf(acc[2*m+1] + bdv);
            dst[m] = lo | (hi << 16);
        }
        __syncthreads();
    }
}

__global__ __launch_bounds__(256) void k_attn_fe1(
    const float* __restrict__ x, const float* __restrict__ fb,
    const float* __restrict__ fc, const u16* __restrict__ fd,
    const float* __restrict__ alpha, u16* __restrict__ xf2)
{
    if (alpha[0] == 0.f) return;
    __shared__ __align__(16) float smem[12800];
    float* fbt = smem;
    float* fct = smem + 512;
    float* S   = smem + 8704;
    float* attnT = smem + 512;
    const int t = threadIdx.x;
    for (int id = blockIdx.x; id < 16 * 512; id += gridDim.x) {
        const int tile = id & 15;
        const int b = id >> 4;
        #pragma unroll
        for (int s = 0; s < 2; ++s) {
            int j = t + 256 * s;
            int o = j >> 4, l = j & 15;
            fbt[o * 16 + l] = fb[((size_t)b * C8_ + o) * 256 + tile * 16 + l];
        }
        #pragma unroll
        for (int s = 0; s < 32; ++s) {
            int j = t + 256 * s;
            int o = j >> 8, m = j & 255;
            fct[o * 256 + m] = fc[((size_t)b * C8_ + o) * 256 + m];
        }
        __syncthreads();
        {
            const int lane = t & 63, wv = t >> 6;
            float acc[4][4];
            #pragma unroll
            for (int i = 0; i < 4; ++i)
                #pragma unroll
                for (int j = 0; j < 4; ++j) acc[i][j] = 0.f;
            for (int o = 0; o < 32; ++o) {
                float cv[4];
                #pragma unroll
                for (int j = 0; j < 4; ++j) cv[j] = fct[o * 256 + lane + 64 * j];
                #pragma unroll
                for (int i = 0; i < 4; ++i) {
                    float a = fbt[o * 16 + wv * 4 + i];
                    #pragma unroll
                    for (int j = 0; j < 4; ++j) acc[i][j] += a * cv[j];
                }
            }
            #pragma unroll
            for (int i = 0; i < 4; ++i)
                #pragma unroll
                for (int j = 0; j < 4; ++j)
                    S[(wv * 4 + i) * 256 + lane + 64 * j] = acc[i][j];
        }
        __syncthreads();
        {
            const int r = t >> 4, k = t & 15;
            float vals[16];
            float mx = -1e30f;
            #pragma unroll
            for (int j = 0; j < 16; ++j) {
                vals[j] = S[r * 256 + k + 16 * j];
                mx = fmaxf(mx, vals[j]);
            }
            mx = fmaxf(mx, __shfl_xor(mx, 1, 16));
            mx = fmaxf(mx, __shfl_xor(mx, 2, 16));
            mx = fmaxf(mx, __shfl_xor(mx, 4, 16));
            mx = fmaxf(mx, __shfl_xor(mx, 8, 16));
            float sum = 0.f;
            #pragma unroll
            for (int j = 0; j < 16; ++j) { vals[j] = __expf(vals[j] - mx); sum += vals[j]; }
            sum += __shfl_xor(sum, 1, 16);
            sum += __shfl_xor(sum, 2, 16);
            sum += __shfl_xor(sum, 4, 16);
            sum += __shfl_xor(sum, 8, 16);
            const float inv = 1.0f / sum;
            #pragma unroll
            for (int j = 0; j < 16; ++j)
                attnT[(k + 16 * j) * 16 + r] = vals[j] * inv;
        }
        __syncthreads();
        const int c = t;
        float acc[16];
        #pragma unroll
        for (int i = 0; i < 16; ++i) acc[i] = 0.f;
        const u16* fdrow = fd + ((size_t)b * C_ + c) * 256;
        for (int m = 0; m < 256; m += 4) {
            uint2 p = *(const uint2*)(fdrow + m);
            float wm[4] = { bf2f(p.x & 0xffffu), bf2f(p.x >> 16),
                            bf2f(p.y & 0xffffu), bf2f(p.y >> 16) };
            #pragma unroll
            for (int mm = 0; mm < 4; ++mm) {
                const float4* ar = (const float4*)(attnT + (m + mm) * 16);
                float wv = wm[mm];
                #pragma unroll
                for (int qq = 0; qq < 4; ++qq) {
                    float4 av = ar[qq];
                    acc[qq*4+0] += wv * av.x;
                    acc[qq*4+1] += wv * av.y;
                    acc[qq*4+2] += wv * av.z;
                    acc[qq*4+3] += wv * av.w;
                }
            }
        }
        const float al = alpha[0];
        const int n = b >> 6, ph = (b >> 3) & 7, pw = b & 7;
        const int l2 = ph * 8 + pw;
        const float* xb = x + (size_t)n * C_ * HW_ + (size_t)c * HW_;
        #pragma unroll
        for (int i = 0; i < 16; ++i) {
            int l1 = tile * 16 + i;
            int qh = l1 >> 4, qw = l1 & 15;
            float xv = xb[(qh * 8 + ph) * W_ + (qw * 8 + pw)];
            size_t b2 = (size_t)n * 256 + qh * 16 + qw;
            xf2[(b2 * 64 + l2) * 256 + c] = f2bf(al * acc[i] + xv);
        }
        __syncthreads();
    }
}

// ---------------------------------------------------------------------------
// K6: fully-fused PAM2 per b2, with INPUT GATHER FUSED IN (k_gather deleted).
// Fast path (alpha1==0): stage x[n][:, qh*8..+8, qw*8..+8] fp32->bf16 into
// LDS tile XT[64 l][264] (pad-8 stride for bank stagger). General path:
// stage from xf2 (written by k_attn_fe1). Residual is read at the output
// addresses in the final store (same NCHW address as the store; fp32-exact
// on the fast path). Phases SPLIT as in R0 (merge regressed: R5 194 us —
// register pressure killed cross-iteration prefetch).
// LDS (u16): region0 = XT [64][264] (16896) / FDSLAB [256][72] (18432) /
// stg f32[64][133] — time-shared; FBCT @18432 (4608); ATTN @23040 (4608).
// Total 27648 u16 = 55296 B -> 2 blocks/CU unchanged.
// Barriers: B0 post-stage; B1 post-FBCT (as R0); B2 after phase-5 K-loop
// (all XT reads done) before FDSLAB overlays XT; B3 after FDSLAB stores.
// ---------------------------------------------------------------------------
#define XT     0
#define FDSLAB 0
#define FBCT   18432
#define ATTN   23040

__global__ __launch_bounds__(256) void k_pam2_fused(
    const float* __restrict__ x, const u16* __restrict__ xf2,
    const u16* __restrict__ Wbc2, const u16* __restrict__ Wd2,
    const float* __restrict__ bb2, const float* __restrict__ bc2,
    const float* __restrict__ bd2, const float* __restrict__ alpha1,
    const float* __restrict__ alpha2, float* __restrict__ out)
{
    __shared__ __align__(16) u16 lds[27648];
    const int b2 = blockIdx.x;
    const int n = b2 >> 8, qh = (b2 >> 4) & 15, qw = b2 & 15;
    const int t = threadIdx.x;
    const int w = t >> 6, lane = t & 63;
    const int q = lane >> 4, i = lane & 15;
    const int ls = w * 16;   // wave's l-strip (phases 1,3,6)
    const bool fast = (alpha1[0] == 0.f);
    const float* xblk = x + (size_t)n * 256 * HW_ + (qh * 8) * W_ + qw * 8;
    const u16* xr2 = xf2 + (size_t)b2 * 64 * 256;

    // ---- phase 0: stage input tile -> XT[64][264] bf16
    if (fast) {
        #pragma unroll
        for (int jj = 0; jj < 16; ++jj) {
            int idx = jj * 256 + t;               // 0..4095 = 256c x 8ph x 2pw4
            int pw4 = idx & 1, c = (idx >> 1) & 255, ph = idx >> 9;
            float4 v = *(const float4*)(xblk + (size_t)c * HW_ + ph * W_ + pw4 * 4);
            int l0 = ph * 8 + pw4 * 4;
            lds[XT + (l0 + 0) * 264 + c] = f2bf(v.x);
            lds[XT + (l0 + 1) * 264 + c] = f2bf(v.y);
            lds[XT + (l0 + 2) * 264 + c] = f2bf(v.z);
            lds[XT + (l0 + 3) * 264 + c] = f2bf(v.w);
        }
    } else {
        #pragma unroll
        for (int m = 0; m < 16; ++m) {
            int idx = m * 256 + t;                // 0..4095 u32-pairs
            int row = idx >> 6, cp = idx & 63;
            u32 vv = *(const u32*)(xr2 + (size_t)row * 256 + cp * 2);
            *(u32*)((char*)lds + row * 528 + cp * 4) = vv;
        }
    }
    __syncthreads();   // B0

    // ---- phase 1: fbc2[o][l] = Wbc2 @ XT^T (M=64 o, N=16 l per wave, K=256)
    f32x4_t acc1[4];
    #pragma unroll
    for (int mt = 0; mt < 4; ++mt) acc1[mt] = (f32x4_t){0.f,0.f,0.f,0.f};
    for (int ks = 0; ks < 8; ++ks) {
        int kb = ks * 32 + q * 8;
        bf16x8_t bfr = ld_frag(&lds[XT + (ls + i) * 264 + kb]);
        #pragma unroll
        for (int mt = 0; mt < 4; ++mt) {
            bf16x8_t afr = ld_frag(Wbc2 + (mt * 16 + i) * 256 + kb);
            acc1[mt] = __builtin_amdgcn_mfma_f32_16x16x32_bf16(afr, bfr, acc1[mt], 0, 0, 0);
        }
    }
    // bias + transpose-store fbcT[l][o]
    #pragma unroll
    for (int mt = 0; mt < 4; ++mt) {
        #pragma unroll
        for (int r = 0; r < 4; ++r) {
            int o = mt * 16 + q * 4 + r;
            float bv = (o < 32) ? bb2[o] : bc2[o - 32];
            lds[FBCT + (ls + i) * 72 + o] = f2bf(acc1[mt][r] + bv);
        }
    }
    __syncthreads();   // B1

    // ---- phase 3: S[l][m] = fbT @ fcT^T (M=16 l, N=64 m, K=32 o)
    f32x4_t accS[4];
    #pragma unroll
    for (int nt = 0; nt < 4; ++nt) accS[nt] = (f32x4_t){0.f,0.f,0.f,0.f};
    {
        bf16x8_t afr = ld_frag(&lds[FBCT + (ls + i) * 72 + q * 8]);
        #pragma unroll
        for (int nt = 0; nt < 4; ++nt) {
            bf16x8_t bfr = ld_frag(&lds[FBCT + (nt * 16 + i) * 72 + 32 + q * 8]);
            accS[nt] = __builtin_amdgcn_mfma_f32_16x16x32_bf16(afr, bfr, accS[nt], 0, 0, 0);
        }
    }
    // ---- phase 4: softmax rows -> attn bf16 [l][m] (wave-local rows; no barrier)
    #pragma unroll
    for (int r = 0; r < 4; ++r) {
        int l = ls + q * 4 + r;
        float mx = accS[0][r];
        #pragma unroll
        for (int nt = 1; nt < 4; ++nt) mx = fmaxf(mx, accS[nt][r]);
        mx = fmaxf(mx, __shfl_xor(mx, 1));
        mx = fmaxf(mx, __shfl_xor(mx, 2));
        mx = fmaxf(mx, __shfl_xor(mx, 4));
        mx = fmaxf(mx, __shfl_xor(mx, 8));
        float e[4], sum = 0.f;
        #pragma unroll
        for (int nt = 0; nt < 4; ++nt) { e[nt] = __expf(accS[nt][r] - mx); sum += e[nt]; }
        sum += __shfl_xor(sum, 1);
        sum += __shfl_xor(sum, 2);
        sum += __shfl_xor(sum, 4);
        sum += __shfl_xor(sum, 8);
        float inv = 1.0f / sum;
        #pragma unroll
        for (int nt = 0; nt < 4; ++nt)
            lds[ATTN + l * 72 + nt * 16 + i] = f2bf(e[nt] * inv);
    }

    // ---- phase 5: fd2[c][m] = Wd2 @ XT^T (per wave M=64 c, N=64 m, K=256)
    {
        const int cs = w * 64;
        f32x4_t acc2[4][4];
        #pragma unroll
        for (int mt = 0; mt < 4; ++mt)
            #pragma unroll
            for (int nt = 0; nt < 4; ++nt) acc2[mt][nt] = (f32x4_t){0.f,0.f,0.f,0.f};
        for (int ks = 0; ks < 8; ++ks) {
            int kb = ks * 32 + q * 8;
            bf16x8_t bfr[4];
            #pragma unroll
            for (int nt = 0; nt < 4; ++nt)
                bfr[nt] = ld_frag(&lds[XT + (nt * 16 + i) * 264 + kb]);
            #pragma unroll
            for (int mt = 0; mt < 4; ++mt) {
                bf16x8_t afr = ld_frag(Wd2 + (size_t)(cs + mt * 16 + i) * 256 + kb);
                #pragma unroll
                for (int nt = 0; nt < 4; ++nt)
                    acc2[mt][nt] = __builtin_amdgcn_mfma_f32_16x16x32_bf16(afr, bfr[nt], acc2[mt][nt], 0, 0, 0);
            }
        }
        __syncthreads();   // B2: all waves done reading XT (FDSLAB overlays it)
        #pragma unroll
        for (int mt = 0; mt < 4; ++mt) {
            #pragma unroll
            for (int r = 0; r < 4; ++r) {
                int c = cs + mt * 16 + q * 4 + r;
                float bv = bd2[c];
                #pragma unroll
                for (int nt = 0; nt < 4; ++nt)
                    lds[FDSLAB + c * 72 + nt * 16 + i] = f2bf(acc2[mt][nt][r] + bv);
            }
        }
    }
    __syncthreads();   // B3

    // ---- phase 6: fe[l][c] = attn @ fd^T (per wave M=16 l, N=256 c, K=64 m)
    f32x4_t accE[16];
    #pragma unroll
    for (int nt = 0; nt < 16; ++nt) accE[nt] = (f32x4_t){0.f,0.f,0.f,0.f};
    #pragma unroll
    for (int ks = 0; ks < 2; ++ks) {
        int kb = ks * 32 + q * 8;
        bf16x8_t afr = ld_frag(&lds[ATTN + (ls + i) * 72 + kb]);
        #pragma unroll
        for (int nt = 0; nt < 16; ++nt) {
            bf16x8_t bfr = ld_frag(&lds[FDSLAB + (nt * 16 + i) * 72 + kb]);
            accE[nt] = __builtin_amdgcn_mfma_f32_16x16x32_bf16(afr, bfr, accE[nt], 0, 0, 0);
        }
    }

    // ---- phase 7: alpha*fe staged via LDS; residual added at the store from
    // the source tensor at the SAME address as the out write (coalesced).
    const float al = alpha2[0];
    float vals[64];
    #pragma unroll
    for (int nt = 0; nt < 16; ++nt) {
        #pragma unroll
        for (int r = 0; r < 4; ++r)
            vals[nt * 4 + r] = al * accE[nt][r];
    }
    float* stg = (float*)lds;   // overlays region0: [64][133] floats
    for (int h = 0; h < 2; ++h) {
        __syncthreads();
        #pragma unroll
        for (int nt = h * 8; nt < h * 8 + 8; ++nt) {
            #pragma unroll
            for (int r = 0; r < 4; ++r) {
                int l = ls + q * 4 + r;
                int cc = nt * 16 + i - h * 128;
                stg[l * 133 + cc] = vals[nt * 4 + r];
            }
        }
        __syncthreads();
        int ph = lane >> 3, pw = lane & 7;
        if (fast) {
            for (int j = 0; j < 32; ++j) {
                int c = h * 128 + w * 32 + j;
                float v = stg[lane * 133 + (c - h * 128)];
                float xv = xblk[(size_t)c * HW_ + ph * W_ + pw];
                out[(((size_t)n * 256 + c) * 128 + qh * 8 + ph) * 128 + qw * 8 + pw] = v + xv;
            }
        } else {
            for (int j = 0; j < 32; ++j) {
                int c = h * 128 + w * 32 + j;
                float v = stg[lane * 133 + (c - h * 128)];
                float xv = bf2f(xr2[(size_t)lane * 256 + c]);   // l == lane
                out[(((size_t)n * 256 + c) * 128 + qh * 8 + ph) * 128 + qw * 8 + pw] = v + xv;
            }
        }
    }
}

extern "C" void kernel_launch(void* const* d_in, const int* in_sizes, int n_in,
                              void* d_out, int out_size, void* d_ws, size_t ws_size,
                              hipStream_t stream)
{
    const float* x   = (const float*)d_in[0];
    const float* Wb1 = (const float*)d_in[1];
    const float* bb1 = (const float*)d_in[2];
    const float* Wc1 = (const float*)d_in[3];
    const float* bc1 = (const float*)d_in[4];
    const float* Wd1 = (const float*)d_in[5];
    const float* bd1 = (const float*)d_in[6];
    const float* a1  = (const float*)d_in[7];
    const float* Wb2 = (const float*)d_in[8];
    const float* bb2 = (const float*)d_in[9];
    const float* Wc2 = (const float*)d_in[10];
    const float* bc2 = (const float*)d_in[11];
    const float* Wd2 = (const float*)d_in[12];
    const float* bd2 = (const float*)d_in[13];
    const float* a2  = (const float*)d_in[14];
    (void)in_sizes; (void)n_in; (void)out_size; (void)ws_size;

    char* ws = (char*)d_ws;
    u16*   xf2  = (u16*)(ws + WS_XF2);
    u16*   Wbc2 = (u16*)(ws + WS_WBC2);
    u16*   Wd2b = (u16*)(ws + WS_WD2);
    float* fb1  = (float*)(ws + WS_FB1);
    float* fc1  = (float*)(ws + WS_FC1);
    u16*   fd1  = (u16*)(ws + WS_FD1);
    float* out  = (float*)d_out;

    k_wpack<<<dim3(320), 256, 0, stream>>>(Wb2, Wc2, Wd2, Wbc2, Wd2b);
    // PAM1 general path (grid-strided; early-exits when alpha1 == 0)
    k_fbfc1<<<dim3(512), 256, 0, stream>>>(x, Wb1, bb1, Wc1, bc1, fb1, fc1, a1);
    k_fd1<<<dim3(512), 256, 0, stream>>>(x, Wd1, bd1, fd1, a1);
    k_attn_fe1<<<dim3(512), 256, 0, stream>>>(x, fb1, fc1, fd1, a1, xf2);
    // PAM2 fused (gather fused in; fast path reads x directly)
    k_pam2_fused<<<dim3(2048), 256, 0, stream>>>(x, xf2, Wbc2, Wd2b, bb2, bc2, bd2, a1, a2, out);
}

// Round 7
// 342.891 us; speedup vs baseline: 1.2943x; 1.2442x over previous
//
#include <hip/hip_runtime.h>
#include <stdint.h>

typedef unsigned int u32;
typedef unsigned short u16;

#define C_   256
#define C8_  32
#define H_   128
#define W_   128
#define HW_  (H_*W_)

typedef __bf16 bf16x8_t __attribute__((ext_vector_type(8)));
typedef float  f32x4_t  __attribute__((ext_vector_type(4)));

__device__ __forceinline__ float bf2f(u32 u) {
    union { u32 i; float f; } v; v.i = u << 16; return v.f;
}
__device__ __forceinline__ u16 f2bf(float f) {
    union { float f; u32 i; } v; v.f = f;
    u32 r = v.i + 0x7fffu + ((v.i >> 16) & 1u);
    return (u16)(r >> 16);
}
__device__ __forceinline__ bf16x8_t ld_frag(const u16* p) {
    union { uint4 u; bf16x8_t b; } x; x.u = *(const uint4*)p; return x.b;
}

// ws layout (bytes)
#define WS_XF1   0                  // (unused; layout stability)
#define WS_XF2   67108864           // bf16 [2048][64][256] — general path only
#define WS_WBC2  134217728          // bf16 [64][256]        = 32768
#define WS_WD2   (134217728+32768)  // bf16 [256][256]       = 131072
#define WS_GEN   134479872          // general path scratch (only touched if alpha1 != 0)
#define WS_FB1   WS_GEN                       // fp32 [512][32][256] = 16777216
#define WS_FC1   (WS_GEN + 16777216)          // fp32 [512][32][256] = 16777216
#define WS_FD1   (WS_GEN + 33554432)          // bf16 [512][256][256] = 67108864

// ---------------------------------------------------------------------------
// Kw: pack PAM2 weights to bf16. Wbc2 rows 0..31 = Wb2, 32..63 = Wc2.
// ---------------------------------------------------------------------------
__global__ __launch_bounds__(256) void k_wpack(
    const float* __restrict__ Wb2, const float* __restrict__ Wc2,
    const float* __restrict__ Wd2, u16* __restrict__ Wbc2, u16* __restrict__ Wd2b)
{
    int gid = blockIdx.x * 256 + threadIdx.x;
    if (gid < 16384) {
        int o = gid >> 8, c = gid & 255;
        float v = (o < 32) ? Wb2[o*256 + c] : Wc2[(o-32)*256 + c];
        Wbc2[gid] = f2bf(v);
    } else if (gid < 81920) {
        Wd2b[gid - 16384] = f2bf(Wd2[gid - 16384]);
    }
}

// ---------------------------------------------------------------------------
// General-path PAM1 kernels — grid-strided; early-exit when alpha1 == 0.
// ---------------------------------------------------------------------------
__global__ __launch_bounds__(256) void k_fbfc1(
    const float* __restrict__ x, const float* __restrict__ Wb,
    const float* __restrict__ bb, const float* __restrict__ Wc,
    const float* __restrict__ bc, float* __restrict__ fb, float* __restrict__ fc,
    const float* __restrict__ alpha)
{
    if (alpha[0] == 0.f) return;
    __shared__ __align__(16) float xt[C_ * 32];
    const int t = threadIdx.x;
    for (int id = blockIdx.x; id < 8 * 512; id += gridDim.x) {
        const int tile = id & 7;
        const int b = id >> 3;
        const int n = b >> 6, ph = (b >> 3) & 7, pw = b & 7;
        const float* xb = x + (size_t)n * C_ * HW_;
        #pragma unroll
        for (int s = 0; s < 32; ++s) {
            int i = t + 256 * s;
            int c = i >> 5, l = i & 31;
            int l1 = tile * 32 + l;
            int qh = l1 >> 4, qw = l1 & 15;
            xt[c * 32 + l] = xb[(size_t)c * HW_ + (qh * 8 + ph) * W_ + (qw * 8 + pw)];
        }
        __syncthreads();
        const int l = t & 31;
        const int og = t >> 5;
        const float* Wp = (og < 4) ? Wb : Wc;
        const float* bp = (og < 4) ? bb : bc;
        float* op = (og < 4) ? fb : fc;
        const int ob = (og & 3) * 8;
        float acc[8];
        #pragma unroll
        for (int j = 0; j < 8; ++j) acc[j] = bp[ob + j];
        for (int c = 0; c < C_; ++c) {
            float xv = xt[c * 32 + l];
            #pragma unroll
            for (int j = 0; j < 8; ++j)
                acc[j] += Wp[(ob + j) * C_ + c] * xv;
        }
        #pragma unroll
        for (int j = 0; j < 8; ++j)
            op[((size_t)b * C8_ + ob + j) * 256 + tile * 32 + l] = acc[j];
        __syncthreads();
    }
}

__global__ __launch_bounds__(256) void k_fd1(
    const float* __restrict__ x, const float* __restrict__ Wd,
    const float* __restrict__ bd, u16* __restrict__ fd,
    const float* __restrict__ alpha)
{
    if (alpha[0] == 0.f) return;
    __shared__ __align__(16) float xt[C_ * 32];
    const int t = threadIdx.x;
    for (int id = blockIdx.x; id < 8 * 512; id += gridDim.x) {
        const int tile = id & 7;
        const int b = id >> 3;
        const int n = b >> 6, ph = (b >> 3) & 7, pw = b & 7;
        const float* xb = x + (size_t)n * C_ * HW_;
        #pragma unroll
        for (int s = 0; s < 32; ++s) {
            int i = t + 256 * s;
            int k = i >> 5, m = i & 31;
            int l1 = tile * 32 + m;
            int qh = l1 >> 4, qw = l1 & 15;
            xt[k * 32 + m] = xb[(size_t)k * HW_ + (qh * 8 + ph) * W_ + (qw * 8 + pw)];
        }
        __syncthreads();
        const int c = t;
        float acc[32];
        #pragma unroll
        for (int m = 0; m < 32; ++m) acc[m] = 0.f;
        const float* wrow = Wd + c * C_;
        for (int k = 0; k < C_; k += 4) {
            float4 w = *(const float4*)(wrow + k);
            float wk[4] = {w.x, w.y, w.z, w.w};
            #pragma unroll
            for (int kk = 0; kk < 4; ++kk) {
                const float4* xr = (const float4*)(xt + (k + kk) * 32);
                float wv = wk[kk];
                #pragma unroll
                for (int qq = 0; qq < 8; ++qq) {
                    float4 xv = xr[qq];
                    acc[qq*4+0] += wv * xv.x;
                    acc[qq*4+1] += wv * xv.y;
                    acc[qq*4+2] += wv * xv.z;
                    acc[qq*4+3] += wv * xv.w;
                }
            }
        }
        const float bdv = bd[c];
        u32* dst = (u32*)(fd + ((size_t)b * C_ + c) * 256 + tile * 32);
        #pragma unroll
        for (int m = 0; m < 16; ++m) {
            u32 lo = f2bf(acc[2*m] + bdv);
            u32 hi = f2bf(acc[2*m+1] + bdv);
            dst[m] = lo | (hi << 16);
        }
        __syncthreads();
    }
}

__global__ __launch_bounds__(256) void k_attn_fe1(
    const float* __restrict__ x, const float* __restrict__ fb,
    const float* __restrict__ fc, const u16* __restrict__ fd,
    const float* __restrict__ alpha, u16* __restrict__ xf2)
{
    if (alpha[0] == 0.f) return;
    __shared__ __align__(16) float smem[12800];
    float* fbt = smem;
    float* fct = smem + 512;
    float* S   = smem + 8704;
    float* attnT = smem + 512;
    const int t = threadIdx.x;
    for (int id = blockIdx.x; id < 16 * 512; id += gridDim.x) {
        const int tile = id & 15;
        const int b = id >> 4;
        #pragma unroll
        for (int s = 0; s < 2; ++s) {
            int j = t + 256 * s;
            int o = j >> 4, l = j & 15;
            fbt[o * 16 + l] = fb[((size_t)b * C8_ + o) * 256 + tile * 16 + l];
        }
        #pragma unroll
        for (int s = 0; s < 32; ++s) {
            int j = t + 256 * s;
            int o = j >> 8, m = j & 255;
            fct[o * 256 + m] = fc[((size_t)b * C8_ + o) * 256 + m];
        }
        __syncthreads();
        {
            const int lane = t & 63, wv = t >> 6;
            float acc[4][4];
            #pragma unroll
            for (int i = 0; i < 4; ++i)
                #pragma unroll
                for (int j = 0; j < 4; ++j) acc[i][j] = 0.f;
            for (int o = 0; o < 32; ++o) {
                float cv[4];
                #pragma unroll
                for (int j = 0; j < 4; ++j) cv[j] = fct[o * 256 + lane + 64 * j];
                #pragma unroll
                for (int i = 0; i < 4; ++i) {
                    float a = fbt[o * 16 + wv * 4 + i];
                    #pragma unroll
                    for (int j = 0; j < 4; ++j) acc[i][j] += a * cv[j];
                }
            }
            #pragma unroll
            for (int i = 0; i < 4; ++i)
                #pragma unroll
                for (int j = 0; j < 4; ++j)
                    S[(wv * 4 + i) * 256 + lane + 64 * j] = acc[i][j];
        }
        __syncthreads();
        {
            const int r = t >> 4, k = t & 15;
            float vals[16];
            float mx = -1e30f;
            #pragma unroll
            for (int j = 0; j < 16; ++j) {
                vals[j] = S[r * 256 + k + 16 * j];
                mx = fmaxf(mx, vals[j]);
            }
            mx = fmaxf(mx, __shfl_xor(mx, 1, 16));
            mx = fmaxf(mx, __shfl_xor(mx, 2, 16));
            mx = fmaxf(mx, __shfl_xor(mx, 4, 16));
            mx = fmaxf(mx, __shfl_xor(mx, 8, 16));
            float sum = 0.f;
            #pragma unroll
            for (int j = 0; j < 16; ++j) { vals[j] = __expf(vals[j] - mx); sum += vals[j]; }
            sum += __shfl_xor(sum, 1, 16);
            sum += __shfl_xor(sum, 2, 16);
            sum += __shfl_xor(sum, 4, 16);
            sum += __shfl_xor(sum, 8, 16);
            const float inv = 1.0f / sum;
            #pragma unroll
            for (int j = 0; j < 16; ++j)
                attnT[(k + 16 * j) * 16 + r] = vals[j] * inv;
        }
        __syncthreads();
        const int c = t;
        float acc[16];
        #pragma unroll
        for (int i = 0; i < 16; ++i) acc[i] = 0.f;
        const u16* fdrow = fd + ((size_t)b * C_ + c) * 256;
        for (int m = 0; m < 256; m += 4) {
            uint2 p = *(const uint2*)(fdrow + m);
            float wm[4] = { bf2f(p.x & 0xffffu), bf2f(p.x >> 16),
                            bf2f(p.y & 0xffffu), bf2f(p.y >> 16) };
            #pragma unroll
            for (int mm = 0; mm < 4; ++mm) {
                const float4* ar = (const float4*)(attnT + (m + mm) * 16);
                float wv = wm[mm];
                #pragma unroll
                for (int qq = 0; qq < 4; ++qq) {
                    float4 av = ar[qq];
                    acc[qq*4+0] += wv * av.x;
                    acc[qq*4+1] += wv * av.y;
                    acc[qq*4+2] += wv * av.z;
                    acc[qq*4+3] += wv * av.w;
                }
            }
        }
        const float al = alpha[0];
        const int n = b >> 6, ph = (b >> 3) & 7, pw = b & 7;
        const int l2 = ph * 8 + pw;
        const float* xb = x + (size_t)n * C_ * HW_ + (size_t)c * HW_;
        #pragma unroll
        for (int i = 0; i < 16; ++i) {
            int l1 = tile * 16 + i;
            int qh = l1 >> 4, qw = l1 & 15;
            float xv = xb[(qh * 8 + ph) * W_ + (qw * 8 + pw)];
            size_t b2 = (size_t)n * 256 + qh * 16 + qw;
            xf2[(b2 * 64 + l2) * 256 + c] = f2bf(al * acc[i] + xv);
        }
        __syncthreads();
    }
}

// ---------------------------------------------------------------------------
// K6: fully-fused PAM2 per b2, gather fused (no k_gather kernel).
// R7 fixes over R6 (FETCH 528 MB, dur 240 us):
//  (1) residual captured to 32 VGPRs from the XT LDS tile right after staging
//      (8x ds_read_b128) — phase 7 no longer re-reads x (was 64 scalar global
//      loads/thread + ~260 MB extra FETCH). Residual = bf16, as in R0-R5.
//  (2) chunked XCD swizzle b2=(bid%8)*256+bid/8 — adjacent qw tiles (which
//      share the split 64B x-lines) map to the same XCD's L2.
//  (3) general-path staging loop fixed (R6 only copied cols 0..127).
// Phases split (R0 order), no setprio. LDS 55296 B -> 2 blocks/CU.
// ---------------------------------------------------------------------------
#define XT     0
#define FDSLAB 0
#define FBCT   18432
#define ATTN   23040

__global__ __launch_bounds__(256) void k_pam2_fused(
    const float* __restrict__ x, const u16* __restrict__ xf2,
    const u16* __restrict__ Wbc2, const u16* __restrict__ Wd2,
    const float* __restrict__ bb2, const float* __restrict__ bc2,
    const float* __restrict__ bd2, const float* __restrict__ alpha1,
    const float* __restrict__ alpha2, float* __restrict__ out)
{
    __shared__ __align__(16) u16 lds[27648];
    const int bid = blockIdx.x;
    const int b2 = (bid & 7) * 256 + (bid >> 3);   // chunked XCD swizzle (2048%8==0)
    const int n = b2 >> 8, qh = (b2 >> 4) & 15, qw = b2 & 15;
    const int t = threadIdx.x;
    const int w = t >> 6, lane = t & 63;
    const int q = lane >> 4, i = lane & 15;
    const int ls = w * 16;   // wave's l-strip (phases 1,3,6)
    const bool fast = (alpha1[0] == 0.f);
    const float* xblk = x + (size_t)n * 256 * HW_ + (qh * 8) * W_ + qw * 8;
    const u16* xr2 = xf2 + (size_t)b2 * 64 * 256;

    // ---- phase 0: stage input tile -> XT[64][264] bf16
    if (fast) {
        #pragma unroll
        for (int jj = 0; jj < 16; ++jj) {
            int idx = jj * 256 + t;               // 0..4095 = 256c x 8ph x 2pw4
            int pw4 = idx & 1, c = (idx >> 1) & 255, ph = idx >> 9;
            float4 v = *(const float4*)(xblk + (size_t)c * HW_ + ph * W_ + pw4 * 4);
            int l0 = ph * 8 + pw4 * 4;
            lds[XT + (l0 + 0) * 264 + c] = f2bf(v.x);
            lds[XT + (l0 + 1) * 264 + c] = f2bf(v.y);
            lds[XT + (l0 + 2) * 264 + c] = f2bf(v.z);
            lds[XT + (l0 + 3) * 264 + c] = f2bf(v.w);
        }
    } else {
        #pragma unroll
        for (int m = 0; m < 32; ++m) {
            int idx = m * 256 + t;                // 0..8191 u32-pairs (64r x 128)
            int row = idx >> 7, cp = idx & 127;
            u32 vv = *(const u32*)(xr2 + (size_t)row * 256 + cp * 2);
            *(u32*)((char*)lds + row * 528 + cp * 4) = vv;
        }
    }
    __syncthreads();   // B0

    // ---- residual capture: this thread's 64 out-values' residuals, bf16
    // packed into 32 VGPRs (cols h*128 + w*32 + j at row l==lane).
    u32 rs[32];
    #pragma unroll
    for (int k = 0; k < 8; ++k) {
        int hh = k >> 2, kk = k & 3;
        uint4 v = *(const uint4*)&lds[XT + lane * 264 + hh * 128 + w * 32 + kk * 8];
        rs[k*4+0] = v.x; rs[k*4+1] = v.y; rs[k*4+2] = v.z; rs[k*4+3] = v.w;
    }

    // ---- phase 1: fbc2[o][l] = Wbc2 @ XT^T (M=64 o, N=16 l per wave, K=256)
    f32x4_t acc1[4];
    #pragma unroll
    for (int mt = 0; mt < 4; ++mt) acc1[mt] = (f32x4_t){0.f,0.f,0.f,0.f};
    for (int ks = 0; ks < 8; ++ks) {
        int kb = ks * 32 + q * 8;
        bf16x8_t bfr = ld_frag(&lds[XT + (ls + i) * 264 + kb]);
        #pragma unroll
        for (int mt = 0; mt < 4; ++mt) {
            bf16x8_t afr = ld_frag(Wbc2 + (mt * 16 + i) * 256 + kb);
            acc1[mt] = __builtin_amdgcn_mfma_f32_16x16x32_bf16(afr, bfr, acc1[mt], 0, 0, 0);
        }
    }
    // bias + transpose-store fbcT[l][o]
    #pragma unroll
    for (int mt = 0; mt < 4; ++mt) {
        #pragma unroll
        for (int r = 0; r < 4; ++r) {
            int o = mt * 16 + q * 4 + r;
            float bv = (o < 32) ? bb2[o] : bc2[o - 32];
            lds[FBCT + (ls + i) * 72 + o] = f2bf(acc1[mt][r] + bv);
        }
    }
    __syncthreads();   // B1

    // ---- phase 3: S[l][m] = fbT @ fcT^T (M=16 l, N=64 m, K=32 o)
    f32x4_t accS[4];
    #pragma unroll
    for (int nt = 0; nt < 4; ++nt) accS[nt] = (f32x4_t){0.f,0.f,0.f,0.f};
    {
        bf16x8_t afr = ld_frag(&lds[FBCT + (ls + i) * 72 + q * 8]);
        #pragma unroll
        for (int nt = 0; nt < 4; ++nt) {
            bf16x8_t bfr = ld_frag(&lds[FBCT + (nt * 16 + i) * 72 + 32 + q * 8]);
            accS[nt] = __builtin_amdgcn_mfma_f32_16x16x32_bf16(afr, bfr, accS[nt], 0, 0, 0);
        }
    }
    // ---- phase 4: softmax rows -> attn bf16 [l][m] (wave-local rows; no barrier)
    #pragma unroll
    for (int r = 0; r < 4; ++r) {
        int l = ls + q * 4 + r;
        float mx = accS[0][r];
        #pragma unroll
        for (int nt = 1; nt < 4; ++nt) mx = fmaxf(mx, accS[nt][r]);
        mx = fmaxf(mx, __shfl_xor(mx, 1));
        mx = fmaxf(mx, __shfl_xor(mx, 2));
        mx = fmaxf(mx, __shfl_xor(mx, 4));
        mx = fmaxf(mx, __shfl_xor(mx, 8));
        float e[4], sum = 0.f;
        #pragma unroll
        for (int nt = 0; nt < 4; ++nt) { e[nt] = __expf(accS[nt][r] - mx); sum += e[nt]; }
        sum += __shfl_xor(sum, 1);
        sum += __shfl_xor(sum, 2);
        sum += __shfl_xor(sum, 4);
        sum += __shfl_xor(sum, 8);
        float inv = 1.0f / sum;
        #pragma unroll
        for (int nt = 0; nt < 4; ++nt)
            lds[ATTN + l * 72 + nt * 16 + i] = f2bf(e[nt] * inv);
    }

    // ---- phase 5: fd2[c][m] = Wd2 @ XT^T (per wave M=64 c, N=64 m, K=256)
    {
        const int cs = w * 64;
        f32x4_t acc2[4][4];
        #pragma unroll
        for (int mt = 0; mt < 4; ++mt)
            #pragma unroll
            for (int nt = 0; nt < 4; ++nt) acc2[mt][nt] = (f32x4_t){0.f,0.f,0.f,0.f};
        for (int ks = 0; ks < 8; ++ks) {
            int kb = ks * 32 + q * 8;
            bf16x8_t bfr[4];
            #pragma unroll
            for (int nt = 0; nt < 4; ++nt)
                bfr[nt] = ld_frag(&lds[XT + (nt * 16 + i) * 264 + kb]);
            #pragma unroll
            for (int mt = 0; mt < 4; ++mt) {
                bf16x8_t afr = ld_frag(Wd2 + (size_t)(cs + mt * 16 + i) * 256 + kb);
                #pragma unroll
                for (int nt = 0; nt < 4; ++nt)
                    acc2[mt][nt] = __builtin_amdgcn_mfma_f32_16x16x32_bf16(afr, bfr[nt], acc2[mt][nt], 0, 0, 0);
            }
        }
        __syncthreads();   // B2: all waves done reading XT (FDSLAB overlays it)
        #pragma unroll
        for (int mt = 0; mt < 4; ++mt) {
            #pragma unroll
            for (int r = 0; r < 4; ++r) {
                int c = cs + mt * 16 + q * 4 + r;
                float bv = bd2[c];
                #pragma unroll
                for (int nt = 0; nt < 4; ++nt)
                    lds[FDSLAB + c * 72 + nt * 16 + i] = f2bf(acc2[mt][nt][r] + bv);
            }
        }
    }
    __syncthreads();   // B3

    // ---- phase 6: fe[l][c] = attn @ fd^T (per wave M=16 l, N=256 c, K=64 m)
    f32x4_t accE[16];
    #pragma unroll
    for (int nt = 0; nt < 16; ++nt) accE[nt] = (f32x4_t){0.f,0.f,0.f,0.f};
    #pragma unroll
    for (int ks = 0; ks < 2; ++ks) {
        int kb = ks * 32 + q * 8;
        bf16x8_t afr = ld_frag(&lds[ATTN + (ls + i) * 72 + kb]);
        #pragma unroll
        for (int nt = 0; nt < 16; ++nt) {
            bf16x8_t bfr = ld_frag(&lds[FDSLAB + (nt * 16 + i) * 72 + kb]);
            accE[nt] = __builtin_amdgcn_mfma_f32_16x16x32_bf16(afr, bfr, accE[nt], 0, 0, 0);
        }
    }

    // ---- phase 7: alpha*fe staged via LDS for coalesced NCHW store;
    // residual added from rs[] registers (no global re-read).
    const float al = alpha2[0];
    float* stg = (float*)lds;   // overlays region0: [64][133] floats
    for (int h = 0; h < 2; ++h) {
        __syncthreads();
        #pragma unroll
        for (int nt = h * 8; nt < h * 8 + 8; ++nt) {
            #pragma unroll
            for (int r = 0; r < 4; ++r) {
                int l = ls + q * 4 + r;
                int cc = nt * 16 + i - h * 128;
                stg[l * 133 + cc] = al * accE[nt][r];
            }
        }
        __syncthreads();
        int ph = lane >> 3, pw = lane & 7;
        #pragma unroll
        for (int j = 0; j < 32; ++j) {
            int c = h * 128 + w * 32 + j;
            float v = stg[lane * 133 + (c - h * 128)];
            u32 word = rs[h * 16 + (j >> 1)];
            float xv = bf2f((j & 1) ? (word >> 16) : (word & 0xffffu));
            out[(((size_t)n * 256 + c) * 128 + qh * 8 + ph) * 128 + qw * 8 + pw] = v + xv;
        }
    }
}

extern "C" void kernel_launch(void* const* d_in, const int* in_sizes, int n_in,
                              void* d_out, int out_size, void* d_ws, size_t ws_size,
                              hipStream_t stream)
{
    const float* x   = (const float*)d_in[0];
    const float* Wb1 = (const float*)d_in[1];
    const float* bb1 = (const float*)d_in[2];
    const float* Wc1 = (const float*)d_in[3];
    const float* bc1 = (const float*)d_in[4];
    const float* Wd1 = (const float*)d_in[5];
    const float* bd1 = (const float*)d_in[6];
    const float* a1  = (const float*)d_in[7];
    const float* Wb2 = (const float*)d_in[8];
    const float* bb2 = (const float*)d_in[9];
    const float* Wc2 = (const float*)d_in[10];
    const float* bc2 = (const float*)d_in[11];
    const float* Wd2 = (const float*)d_in[12];
    const float* bd2 = (const float*)d_in[13];
    const float* a2  = (const float*)d_in[14];
    (void)in_sizes; (void)n_in; (void)out_size; (void)ws_size;

    char* ws = (char*)d_ws;
    u16*   xf2  = (u16*)(ws + WS_XF2);
    u16*   Wbc2 = (u16*)(ws + WS_WBC2);
    u16*   Wd2b = (u16*)(ws + WS_WD2);
    float* fb1  = (float*)(ws + WS_FB1);
    float* fc1  = (float*)(ws + WS_FC1);
    u16*   fd1  = (u16*)(ws + WS_FD1);
    float* out  = (float*)d_out;

    k_wpack<<<dim3(320), 256, 0, stream>>>(Wb2, Wc2, Wd2, Wbc2, Wd2b);
    // PAM1 general path (grid-strided; early-exits when alpha1 == 0)
    k_fbfc1<<<dim3(512), 256, 0, stream>>>(x, Wb1, bb1, Wc1, bc1, fb1, fc1, a1);
    k_fd1<<<dim3(512), 256, 0, stream>>>(x, Wd1, bd1, fd1, a1);
    k_attn_fe1<<<dim3(512), 256, 0, stream>>>(x, fb1, fc1, fd1, a1, xf2);
    // PAM2 fused (gather fused in; fast path reads x directly)
    k_pam2_fused<<<dim3(2048), 256, 0, stream>>>(x, xf2, Wbc2, Wd2b, bb2, bc2, bd2, a1, a2, out);
}